// Round 7
// baseline (215.672 us; speedup 1.0000x reference)
//
#include <hip/hip_runtime.h>
#include <math.h>

#define BB 8
#define CC 128
#define NN 4096   // W*H

typedef _Float16 f16;
typedef _Float16 f16x4v __attribute__((ext_vector_type(4)));
typedef _Float16 f16x8 __attribute__((ext_vector_type(8)));
typedef float f32x4v __attribute__((ext_vector_type(4)));
typedef float f32x16 __attribute__((ext_vector_type(16)));

#if __has_builtin(__builtin_amdgcn_exp2f)
#define EXP2(x) __builtin_amdgcn_exp2f(x)
#else
#define EXP2(x) __expf((x)*0.69314718056f)
#endif

// Q rows pre-scaled by 0.25*log2(e): softmax exp is one native v_exp_f32;
// the -SHIFT bias rides in the MFMA C operand.
#define QSCALE 0.360673760222f   // 0.25 * log2(e)
#define SHIFT  5.770780163555f   // 4.0 * log2(e)

// Wf scratch lives in the tail of d_out (attn rewrites d_out afterwards).
#define WF_BYTES 65536

// ---------------------------------------------------------------------------
// prep: stack Wq*QSCALE (rows 0-15), Wk (16-31), Wv (32-159) as f16 in
// 32x32x16 A-fragment order. biasS f32[160] likewise stacked.
// ---------------------------------------------------------------------------
__global__ __launch_bounds__(256)
void prep_kernel(const float* __restrict__ Wq, const float* __restrict__ bq,
                 const float* __restrict__ Wk, const float* __restrict__ bk,
                 const float* __restrict__ Wv, const float* __restrict__ bv,
                 f16* __restrict__ Wf, float* __restrict__ biasS)
{
    const int tg = blockIdx.x*256 + threadIdx.x;   // 0..2559
    if (tg < 2560) {
        const int mt = tg >> 9, ks = (tg >> 6) & 7, l = tg & 63;
        const int n32 = l & 31, h = l >> 5;
        const int r = mt*32 + n32;
        f16x8 v8;
        #pragma unroll
        for (int i = 0; i < 8; i++) {
            int c = ks*16 + 8*h + i;
            float wv_;
            if (r < 16)      wv_ = QSCALE * Wq[r*CC + c];
            else if (r < 32) wv_ = Wk[(r-16)*CC + c];
            else             wv_ = Wv[(r-32)*CC + c];
            v8[i] = (f16)wv_;
        }
        *(f16x8*)&Wf[(size_t)tg*8] = v8;
    }
    if (blockIdx.x == 0 && threadIdx.x < 160) {
        int r = threadIdx.x;
        biasS[r] = r < 16 ? QSCALE*bq[r] : (r < 32 ? bk[r-16] : bv[r-32]);
    }
}

// ---------------------------------------------------------------------------
// Projection as MFMA mini-GEMM: OUT[160][128px] = Wst(160x128) * x(128x128px).
// grid 256 (b = bx&7, pt = bx>>3), block 256 = 4 waves, wave = 32-pixel
// n-tile, K=128 (8 ksteps), 40 MFMAs/wave. Non-temporal x loads keep L2 for
// Qt/Kt/Vf. Epilogue: Qt/Kt pixel-major; V via LDS -> sigma-ordered Vf:
//   Vf[b][kt64][frag=kc*4+ct][l][i] =
//     V[c=ct*32+(l&31)][key=kt64*64 + kc*16 + (i&3)+8*(i>>2)+4*(l>>5)]
// ---------------------------------------------------------------------------
__global__ __launch_bounds__(256)
void proj_kernel(const float* __restrict__ x, const f16* __restrict__ Wf,
                 const float* __restrict__ biasS,
                 f16* __restrict__ Qt, f16* __restrict__ Kt, f16* __restrict__ Vf)
{
    __shared__ __align__(16) f16 Vl[CC*140];   // 35 KB, stride 140 halfs

    const int tid  = threadIdx.x;
    const int lane = tid & 63;
    const int wv   = tid >> 6;
    const int b    = blockIdx.x & 7;
    const int pt   = blockIdx.x >> 3;      // 0..31
    const int n32  = lane & 31;
    const int half = lane >> 5;
    const int p    = pt*128 + wv*32 + n32;

    const float* xp = x + (size_t)b*CC*NN + p;
    f16x8 xf[8];
    #pragma unroll
    for (int ks = 0; ks < 8; ks++) {
        float xv[8];
        #pragma unroll
        for (int i = 0; i < 8; i++)
            xv[i] = __builtin_nontemporal_load(&xp[(size_t)(ks*16 + 8*half + i)*NN]);
        #pragma unroll
        for (int i = 0; i < 8; i++) xf[ks][i] = (f16)xv[i];
    }

    f32x16 acc[5];
    #pragma unroll
    for (int mt = 0; mt < 5; mt++) acc[mt] = (f32x16)0.0f;
    #pragma unroll
    for (int ks = 0; ks < 8; ks++) {
        #pragma unroll
        for (int mt = 0; mt < 5; mt++) {
            f16x8 wfr = *(const f16x8*)&Wf[((size_t)(mt*8 + ks)*64 + lane)*8];
            acc[mt] = __builtin_amdgcn_mfma_f32_32x32x16_f16(wfr, xf[ks], acc[mt], 0, 0, 0);
        }
    }

    #pragma unroll
    for (int mt = 0; mt < 5; mt++) {
        #pragma unroll
        for (int q = 0; q < 4; q++) {
            float4 b4 = *(const float4*)&biasS[mt*32 + q*8 + 4*half];
            acc[mt][q*4+0] += b4.x; acc[mt][q*4+1] += b4.y;
            acc[mt][q*4+2] += b4.z; acc[mt][q*4+3] += b4.w;
        }
    }

    // mt0: rows 0-15 = Q, 16-31 = K
    {
        size_t qkoff = ((size_t)b*NN + p)*16;
        f16x4v s0, s1, s2, s3;
        #pragma unroll
        for (int i = 0; i < 4; i++) {
            s0[i] = (f16)acc[0][i];    s1[i] = (f16)acc[0][4+i];
            s2[i] = (f16)acc[0][8+i];  s3[i] = (f16)acc[0][12+i];
        }
        *(f16x4v*)&Qt[qkoff + 4*half]     = s0;
        *(f16x4v*)&Qt[qkoff + 8 + 4*half] = s1;
        *(f16x4v*)&Kt[qkoff + 4*half]     = s2;
        *(f16x4v*)&Kt[qkoff + 8 + 4*half] = s3;
    }

    // mt1-4: V channels -> LDS [c][local pixel]
    #pragma unroll
    for (int mt = 1; mt < 5; mt++) {
        #pragma unroll
        for (int g = 0; g < 16; g++) {
            int c = (mt-1)*32 + (g & 3) + 8*(g >> 2) + 4*half;
            Vl[c*140 + wv*32 + n32] = (f16)acc[mt][g];
        }
    }
    __syncthreads();

    // sigma-ordered Vf writeout
    #pragma unroll
    for (int pass = 0; pass < 8; pass++) {
        int item = pass*256 + tid;
        int l    = item & 63;
        int f    = (item >> 6) & 15;       // kc*4 + ct
        int ktl  = item >> 10;             // 0..1 (64-px tile within block)
        int c16  = f >> 2, ct = f & 3;
        int li   = l & 31, h2 = l >> 5;
        const f16* src = &Vl[(ct*32 + li)*140 + ktl*64 + c16*16 + 4*h2];
        f16x4v lo = *(const f16x4v*)&src[0];
        f16x4v hi = *(const f16x4v*)&src[8];
        f16x8 v8;
        #pragma unroll
        for (int i = 0; i < 4; i++) { v8[i] = lo[i]; v8[4+i] = hi[i]; }
        int ktg = pt*2 + ktl;              // 64-key tile index
        *(f16x8*)&Vf[((((size_t)b*64 + ktg)*16 + c16*4 + ct)*64 + l)*8] = v8;
    }
}

// ---------------------------------------------------------------------------
// Attention r15 = r10 + DEPTH-2 K/V prefetch (A/B register double-buffer,
// manual 2x unroll, static indices) + lgkm-only barrier.
// Evidence (r8-r14): achieved L2 read BW tracks outstanding-load depth, not
// schedule: r8 16-deep/wave -> 20.6 TB/s; r10 8-deep -> 12.3; r14 4-deep x
// 2x waves -> 18.2. Latency-bound streaming (Little's law at ~200-400cyc L2
// latency), floor = 666 MB / achieved BW; MFMA (16us) and VALU (17us) sit
// below it. Depth-2 doubles in-flight bytes (~20 b128/wave); the lgkm-only
// barrier keeps them in flight across the P-exchange (r10's __syncthreads
// drained vmcnt each iter, capping effective depth at intra-iter).
// Traffic unchanged (V read once/block). No PV-split (r13 regression).
// Regs: ~210 unified (vpfA/B 64, kfA/B 32, of 64 AGPR) -> 2 waves/SIMD,
// under the 256 spill line. Spill canary: FETCH/WRITE bloat.
// ---------------------------------------------------------------------------
__global__ __launch_bounds__(256, 2)
void attn_kernel(const f16* __restrict__ Qt, const f16* __restrict__ Kt,
                 const f16* __restrict__ Vf, float* __restrict__ out)
{
    __shared__ __align__(16) unsigned char lds_raw[53504];
    // main loop:  Pex [4 waves][2 buf][4 kc][64 lanes][16B] = 32 KB at 0
    // epilogue:   combine regions 2 x 9216 at 0; ls_inv f32[64] at 18432;
    //             Tb f32[128][68] at 18688 (alias Pex; phases barriered)

    const int tid  = threadIdx.x;
    const int lane = tid & 63;
    const int w    = tid >> 6;
    const int cp   = w & 1;            // channel pair + q-tile ownership
    const int kh   = w >> 1;           // key half: kt = kh (mod 2)
    const int b    = blockIdx.x & 7;
    const int qt   = blockIdx.x >> 3;  // 0..63
    const int q0   = qt*64;
    const int n32  = lane & 31;
    const int half = lane >> 5;

    const f16* vb = Vf + (size_t)b*64*16*512;
    const f16* kb = Kt + (size_t)b*NN*16;
    // own q-tile only: A (q0..q0+31) if cp==0, B (q0+32..) if cp==1
    const f16x8 qf = *(const f16x8*)&Qt[((size_t)b*NN + q0 + cp*32 + n32)*16 + half*8];

    f32x16 ofA[2], ofB[2];
    #pragma unroll
    for (int c = 0; c < 2; c++) { ofA[c] = (f32x16)0.0f; ofB[c] = (f32x16)0.0f; }
    float ps[4] = {0.f, 0.f, 0.f, 0.f};

    // ---- depth-2 prologue: K(kh),K(kh+2) and V(kh),V(kh+2) in flight ----
    f16x8 kfA0 = *(const f16x8*)&kb[((size_t)kh*64 + n32)*16 + half*8];
    f16x8 kfA1 = *(const f16x8*)&kb[((size_t)kh*64 + 32 + n32)*16 + half*8];
    f16x8 kfB0 = *(const f16x8*)&kb[((size_t)(kh+2)*64 + n32)*16 + half*8];
    f16x8 kfB1 = *(const f16x8*)&kb[((size_t)(kh+2)*64 + 32 + n32)*16 + half*8];
    f16x8 vpfA[8], vpfB[8];
    {
        const f16* vtA = vb + (size_t)kh*8192;
        const f16* vtB = vb + (size_t)(kh+2)*8192;
        #pragma unroll
        for (int kc = 0; kc < 4; kc++)
            #pragma unroll
            for (int j = 0; j < 2; j++) {
                vpfA[kc*2+j] = *(const f16x8*)&vtA[((size_t)(kc*4 + 2*cp + j)*64 + lane)*8];
                vpfB[kc*2+j] = *(const f16x8*)&vtB[((size_t)(kc*4 + 2*cp + j)*64 + lane)*8];
            }
    }

    f16* Pex = (f16*)lds_raw;
    int pb = 0;
    const int klast = kh + 62;         // last tile for this wave's parity

    // STEP(KT, KF0, KF1, VPF): compute tile KT (K in KF0/KF1, V in VPF),
    // prefetch tile KT+4 into the same registers (clamped dummy at the end).
#define STEP(KT, KF0, KF1, VPF)                                                       \
    {                                                                                 \
        f32x16 St0 = __builtin_amdgcn_mfma_f32_32x32x16_f16(KF0, qf, (f32x16)(-SHIFT), 0, 0, 0); \
        f32x16 St1 = __builtin_amdgcn_mfma_f32_32x32x16_f16(KF1, qf, (f32x16)(-SHIFT), 0, 0, 0); \
        int tl = (KT) + 4; if (tl > klast) tl = (KT);                                 \
        KF0 = *(const f16x8*)&kb[((size_t)tl*64 + n32)*16 + half*8];                  \
        KF1 = *(const f16x8*)&kb[((size_t)tl*64 + 32 + n32)*16 + half*8];             \
        f16x8 po[4];                                                                  \
        _Pragma("unroll")                                                             \
        for (int g = 0; g < 16; g++) {                                                \
            float e0 = EXP2(St0[g]); ps[g & 3] += e0; po[(g >> 3)][g & 7]     = (f16)e0; \
            float e1 = EXP2(St1[g]); ps[g & 3] += e1; po[2 + (g >> 3)][g & 7] = (f16)e1; \
        }                                                                             \
        {                                                                             \
            f16* wr = &Pex[((size_t)(w*2 + pb)*4*64 + lane)*8];                       \
            _Pragma("unroll")                                                         \
            for (int kc = 0; kc < 4; kc++) *(f16x8*)&wr[kc*512] = po[kc];             \
        }                                                                             \
        asm volatile("s_waitcnt lgkmcnt(0)\n\ts_barrier" ::: "memory");               \
        f16x8 pq[4];                                                                  \
        {                                                                             \
            const f16* rd = &Pex[((size_t)((w^1)*2 + pb)*4*64 + lane)*8];             \
            _Pragma("unroll")                                                         \
            for (int kc = 0; kc < 4; kc++) pq[kc] = *(const f16x8*)&rd[kc*512];       \
        }                                                                             \
        const f16* vtn = vb + (size_t)tl*8192;                                        \
        _Pragma("unroll")                                                             \
        for (int kc = 0; kc < 4; kc++) {                                              \
            _Pragma("unroll")                                                         \
            for (int j = 0; j < 2; j++) {                                             \
                const int ii = kc*2 + j;                                              \
                f16x8 vc = VPF[ii];                                                   \
                VPF[ii] = *(const f16x8*)&vtn[((size_t)(kc*4 + 2*cp + j)*64 + lane)*8]; \
                if (cp == 0) {                                                        \
                    ofA[j] = __builtin_amdgcn_mfma_f32_32x32x16_f16(po[kc], vc, ofA[j], 0, 0, 0); \
                    ofB[j] = __builtin_amdgcn_mfma_f32_32x32x16_f16(pq[kc], vc, ofB[j], 0, 0, 0); \
                } else {                                                              \
                    ofA[j] = __builtin_amdgcn_mfma_f32_32x32x16_f16(pq[kc], vc, ofA[j], 0, 0, 0); \
                    ofB[j] = __builtin_amdgcn_mfma_f32_32x32x16_f16(po[kc], vc, ofB[j], 0, 0, 0); \
                }                                                                     \
            }                                                                         \
        }                                                                             \
        pb ^= 1;                                                                      \
    }

    // tiles kh+4i (A) and kh+4i+2 (B); 15 pairs cover kh..kh+58
    for (int it = 0; it < 15; ++it) {
        const int kt = kh + it*4;
        STEP(kt,     kfA0, kfA1, vpfA)
        STEP(kt + 2, kfB0, kfB1, vpfB)
    }
    STEP(kh + 60, kfA0, kfA1, vpfA)   // prefetch clamps to dummy reload
    // final tile kh+62: K in kfB, V in vpfB, no prefetch
    {
        f32x16 St0 = __builtin_amdgcn_mfma_f32_32x32x16_f16(kfB0, qf, (f32x16)(-SHIFT), 0, 0, 0);
        f32x16 St1 = __builtin_amdgcn_mfma_f32_32x32x16_f16(kfB1, qf, (f32x16)(-SHIFT), 0, 0, 0);
        f16x8 po[4];
        #pragma unroll
        for (int g = 0; g < 16; g++) {
            float e0 = EXP2(St0[g]); ps[g & 3] += e0; po[(g >> 3)][g & 7]     = (f16)e0;
            float e1 = EXP2(St1[g]); ps[g & 3] += e1; po[2 + (g >> 3)][g & 7] = (f16)e1;
        }
        {
            f16* wr = &Pex[((size_t)(w*2 + pb)*4*64 + lane)*8];
            #pragma unroll
            for (int kc = 0; kc < 4; kc++) *(f16x8*)&wr[kc*512] = po[kc];
        }
        asm volatile("s_waitcnt lgkmcnt(0)\n\ts_barrier" ::: "memory");
        f16x8 pq[4];
        {
            const f16* rd = &Pex[((size_t)((w^1)*2 + pb)*4*64 + lane)*8];
            #pragma unroll
            for (int kc = 0; kc < 4; kc++) pq[kc] = *(const f16x8*)&rd[kc*512];
        }
        #pragma unroll
        for (int kc = 0; kc < 4; kc++) {
            #pragma unroll
            for (int j = 0; j < 2; j++) {
                f16x8 vc = vpfB[kc*2+j];
                if (cp == 0) {
                    ofA[j] = __builtin_amdgcn_mfma_f32_32x32x16_f16(po[kc], vc, ofA[j], 0, 0, 0);
                    ofB[j] = __builtin_amdgcn_mfma_f32_32x32x16_f16(pq[kc], vc, ofB[j], 0, 0, 0);
                } else {
                    ofA[j] = __builtin_amdgcn_mfma_f32_32x32x16_f16(pq[kc], vc, ofA[j], 0, 0, 0);
                    ofB[j] = __builtin_amdgcn_mfma_f32_32x32x16_f16(po[kc], vc, ofB[j], 0, 0, 0);
                }
            }
        }
    }
#undef STEP

    // per-lane softmax denominator for own q-tile (this wave's key half)
    float ls = (ps[0] + ps[1]) + (ps[2] + ps[3]);
    ls += __shfl_xor(ls, 32);

    // ---- combine the 2-way key split (wave pairs (0,2) and (1,3)) ----
    __syncthreads();
    if (w >= 2) {
        unsigned char* base = lds_raw + (size_t)cp*9216 + (size_t)lane*144;
        #pragma unroll
        for (int a = 0; a < 4; a++) {        // a = qtsel*2 + ctl
            #pragma unroll
            for (int h = 0; h < 2; h++) {
                f16x8 t;
                #pragma unroll
                for (int jj = 0; jj < 8; jj++)
                    t[jj] = (f16)((a < 2 ? ofA[a & 1] : ofB[a & 1])[h*8 + jj]);
                *(f16x8*)(base + a*32 + h*16) = t;
            }
        }
        *(float*)(base + 128) = ls;          // own q-tile's denominator partial
    }
    __syncthreads();
    if (w < 2) {
        unsigned char* base = lds_raw + (size_t)cp*9216 + (size_t)lane*144;
        #pragma unroll
        for (int a = 0; a < 4; a++) {
            #pragma unroll
            for (int h = 0; h < 2; h++) {
                f16x8 t = *(const f16x8*)(base + a*32 + h*16);
                #pragma unroll
                for (int jj = 0; jj < 8; jj++) {
                    float v = (float)t[jj];
                    if (a < 2) ofA[a & 1][h*8 + jj] += v;
                    else       ofB[a & 1][h*8 + jj] += v;
                }
            }
        }
        ls += *(const float*)(base + 128);
        // lead wave (0,cp) now has the full denominator for q-tile cp
        float* ls_inv = (float*)(lds_raw + 18432);
        if (lane < 32) ls_inv[cp*32 + n32] = 1.f / ls;
    }
    __syncthreads();

    // normalize + transpose into Tb[c][q] (waves 0,1 own 64 channels each)
    if (w < 2) {
        const float* ls_inv = (const float*)(lds_raw + 18432);
        float* Tb = (float*)(lds_raw + 18688);
        #pragma unroll
        for (int qts = 0; qts < 2; qts++) {
            #pragma unroll
            for (int j = 0; j < 4; j++) {
                f32x4v iv = *(const f32x4v*)&ls_inv[qts*32 + 8*j + 4*half];
                #pragma unroll
                for (int ctl = 0; ctl < 2; ctl++) {
                    const int c = (2*cp + ctl)*32 + n32;
                    f32x4v o;
                    #pragma unroll
                    for (int e = 0; e < 4; e++)
                        o[e] = (qts ? ofB[ctl] : ofA[ctl])[4*j + e] * iv[e];
                    *(f32x4v*)&Tb[(size_t)c*68 + qts*32 + 8*j + 4*half] = o;
                }
            }
        }
    }
    __syncthreads();
    {
        const float* Tb = (const float*)(lds_raw + 18688);
        #pragma unroll
        for (int it = 0; it < 8; it++) {
            int idx = it*256 + tid;
            int c = idx >> 4, qg = idx & 15;
            f32x4v v = *(const f32x4v*)&Tb[(size_t)c*68 + qg*4];
            // non-temporal: keep the 16 MB output stream out of L2
            __builtin_nontemporal_store(v,
                (f32x4v*)&out[((size_t)b*CC + c)*NN + q0 + qg*4]);
        }
    }
}

extern "C" void kernel_launch(void* const* d_in, const int* in_sizes, int n_in,
                              void* d_out, int out_size, void* d_ws, size_t ws_size,
                              hipStream_t stream) {
    const float* x  = (const float*)d_in[0];
    const float* Wq = (const float*)d_in[1];
    const float* bq = (const float*)d_in[2];
    const float* Wk = (const float*)d_in[3];
    const float* bk = (const float*)d_in[4];
    const float* Wv = (const float*)d_in[5];
    const float* bv = (const float*)d_in[6];
    float* out = (float*)d_out;

    // workspace: Qt,Kt f16 [B][N][16] (1MB each), Vf f16 sigma-fragments (8MB)
    f16* Qw = (f16*)d_ws;
    f16* Kw = Qw + (size_t)BB*NN*16;
    f16* Vw = Kw + (size_t)BB*NN*16;
    unsigned char* tail = (unsigned char*)d_out + (size_t)out_size*4 - WF_BYTES;
    f16*   Wf    = (f16*)tail;
    float* biasS = (float*)(tail + 49152);

    hipLaunchKernelGGL(prep_kernel, dim3(10), dim3(256), 0, stream,
                       Wq, bq, Wk, bk, Wv, bv, Wf, biasS);
    hipLaunchKernelGGL(proj_kernel, dim3(256), dim3(256), 0, stream,
                       x, Wf, biasS, Qw, Kw, Vw);
    hipLaunchKernelGGL(attn_kernel, dim3(512), dim3(256), 0, stream,
                       Qw, Kw, Vw, out);
}

// Round 8
// 148.756 us; speedup vs baseline: 1.4498x; 1.4498x over previous
//
#include <hip/hip_runtime.h>
#include <math.h>

#define BB 8
#define CC 128
#define NN 4096   // W*H

typedef _Float16 f16;
typedef _Float16 f16x4v __attribute__((ext_vector_type(4)));
typedef _Float16 f16x8 __attribute__((ext_vector_type(8)));
typedef float f32x4v __attribute__((ext_vector_type(4)));
typedef float f32x16 __attribute__((ext_vector_type(16)));

#if __has_builtin(__builtin_amdgcn_exp2f)
#define EXP2(x) __builtin_amdgcn_exp2f(x)
#else
#define EXP2(x) __expf((x)*0.69314718056f)
#endif

// Q rows pre-scaled by 0.25*log2(e): softmax exp is one native v_exp_f32;
// the -SHIFT bias rides in the MFMA C operand.
#define QSCALE 0.360673760222f   // 0.25 * log2(e)
#define SHIFT  5.770780163555f   // 4.0 * log2(e)

// Wf scratch lives in the tail of d_out (attn rewrites d_out afterwards).
#define WF_BYTES 65536

// ---------------------------------------------------------------------------
// prep: stack Wq*QSCALE (rows 0-15), Wk (16-31), Wv (32-159) as f16 in
// 32x32x16 A-fragment order. biasS f32[160] likewise stacked.
// ---------------------------------------------------------------------------
__global__ __launch_bounds__(256)
void prep_kernel(const float* __restrict__ Wq, const float* __restrict__ bq,
                 const float* __restrict__ Wk, const float* __restrict__ bk,
                 const float* __restrict__ Wv, const float* __restrict__ bv,
                 f16* __restrict__ Wf, float* __restrict__ biasS)
{
    const int tg = blockIdx.x*256 + threadIdx.x;   // 0..2559
    if (tg < 2560) {
        const int mt = tg >> 9, ks = (tg >> 6) & 7, l = tg & 63;
        const int n32 = l & 31, h = l >> 5;
        const int r = mt*32 + n32;
        f16x8 v8;
        #pragma unroll
        for (int i = 0; i < 8; i++) {
            int c = ks*16 + 8*h + i;
            float wv_;
            if (r < 16)      wv_ = QSCALE * Wq[r*CC + c];
            else if (r < 32) wv_ = Wk[(r-16)*CC + c];
            else             wv_ = Wv[(r-32)*CC + c];
            v8[i] = (f16)wv_;
        }
        *(f16x8*)&Wf[(size_t)tg*8] = v8;
    }
    if (blockIdx.x == 0 && threadIdx.x < 160) {
        int r = threadIdx.x;
        biasS[r] = r < 16 ? QSCALE*bq[r] : (r < 32 ? bk[r-16] : bv[r-32]);
    }
}

// ---------------------------------------------------------------------------
// Projection as MFMA mini-GEMM: OUT[160][128px] = Wst(160x128) * x(128x128px).
// grid 256 (b = bx&7, pt = bx>>3), block 256 = 4 waves, wave = 32-pixel
// n-tile, K=128 (8 ksteps), 40 MFMAs/wave. Non-temporal x loads keep L2 for
// Qt/Kt/Vf. Epilogue: Qt/Kt pixel-major; V via LDS -> sigma-ordered Vf:
//   Vf[b][kt64][frag=kc*4+ct][l][i] =
//     V[c=ct*32+(l&31)][key=kt64*64 + kc*16 + (i&3)+8*(i>>2)+4*(l>>5)]
// ---------------------------------------------------------------------------
__global__ __launch_bounds__(256)
void proj_kernel(const float* __restrict__ x, const f16* __restrict__ Wf,
                 const float* __restrict__ biasS,
                 f16* __restrict__ Qt, f16* __restrict__ Kt, f16* __restrict__ Vf)
{
    __shared__ __align__(16) f16 Vl[CC*140];   // 35 KB, stride 140 halfs

    const int tid  = threadIdx.x;
    const int lane = tid & 63;
    const int wv   = tid >> 6;
    const int b    = blockIdx.x & 7;
    const int pt   = blockIdx.x >> 3;      // 0..31
    const int n32  = lane & 31;
    const int half = lane >> 5;
    const int p    = pt*128 + wv*32 + n32;

    const float* xp = x + (size_t)b*CC*NN + p;
    f16x8 xf[8];
    #pragma unroll
    for (int ks = 0; ks < 8; ks++) {
        float xv[8];
        #pragma unroll
        for (int i = 0; i < 8; i++)
            xv[i] = __builtin_nontemporal_load(&xp[(size_t)(ks*16 + 8*half + i)*NN]);
        #pragma unroll
        for (int i = 0; i < 8; i++) xf[ks][i] = (f16)xv[i];
    }

    f32x16 acc[5];
    #pragma unroll
    for (int mt = 0; mt < 5; mt++) acc[mt] = (f32x16)0.0f;
    #pragma unroll
    for (int ks = 0; ks < 8; ks++) {
        #pragma unroll
        for (int mt = 0; mt < 5; mt++) {
            f16x8 wfr = *(const f16x8*)&Wf[((size_t)(mt*8 + ks)*64 + lane)*8];
            acc[mt] = __builtin_amdgcn_mfma_f32_32x32x16_f16(wfr, xf[ks], acc[mt], 0, 0, 0);
        }
    }

    #pragma unroll
    for (int mt = 0; mt < 5; mt++) {
        #pragma unroll
        for (int q = 0; q < 4; q++) {
            float4 b4 = *(const float4*)&biasS[mt*32 + q*8 + 4*half];
            acc[mt][q*4+0] += b4.x; acc[mt][q*4+1] += b4.y;
            acc[mt][q*4+2] += b4.z; acc[mt][q*4+3] += b4.w;
        }
    }

    // mt0: rows 0-15 = Q, 16-31 = K
    {
        size_t qkoff = ((size_t)b*NN + p)*16;
        f16x4v s0, s1, s2, s3;
        #pragma unroll
        for (int i = 0; i < 4; i++) {
            s0[i] = (f16)acc[0][i];    s1[i] = (f16)acc[0][4+i];
            s2[i] = (f16)acc[0][8+i];  s3[i] = (f16)acc[0][12+i];
        }
        *(f16x4v*)&Qt[qkoff + 4*half]     = s0;
        *(f16x4v*)&Qt[qkoff + 8 + 4*half] = s1;
        *(f16x4v*)&Kt[qkoff + 4*half]     = s2;
        *(f16x4v*)&Kt[qkoff + 8 + 4*half] = s3;
    }

    // mt1-4: V channels -> LDS [c][local pixel]
    #pragma unroll
    for (int mt = 1; mt < 5; mt++) {
        #pragma unroll
        for (int g = 0; g < 16; g++) {
            int c = (mt-1)*32 + (g & 3) + 8*(g >> 2) + 4*half;
            Vl[c*140 + wv*32 + n32] = (f16)acc[mt][g];
        }
    }
    __syncthreads();

    // sigma-ordered Vf writeout
    #pragma unroll
    for (int pass = 0; pass < 8; pass++) {
        int item = pass*256 + tid;
        int l    = item & 63;
        int f    = (item >> 6) & 15;       // kc*4 + ct
        int ktl  = item >> 10;             // 0..1 (64-px tile within block)
        int c16  = f >> 2, ct = f & 3;
        int li   = l & 31, h2 = l >> 5;
        const f16* src = &Vl[(ct*32 + li)*140 + ktl*64 + c16*16 + 4*h2];
        f16x4v lo = *(const f16x4v*)&src[0];
        f16x4v hi = *(const f16x4v*)&src[8];
        f16x8 v8;
        #pragma unroll
        for (int i = 0; i < 4; i++) { v8[i] = lo[i]; v8[4+i] = hi[i]; }
        int ktg = pt*2 + ktl;              // 64-key tile index
        *(f16x8*)&Vf[((((size_t)b*64 + ktg)*16 + c16*4 + ct)*64 + l)*8] = v8;
    }
}

// ---------------------------------------------------------------------------
// Attention r16: V staged through LDS via global_load_lds + counted vmcnt.
// r8-r15 evidence: achieved L2 BW tracks in-flight bytes (16-deep 20.6 TB/s,
// 8-deep 12.3, 4x2 18.2); register prefetch depth >1 tile spills (r11/r12/
// r15, FETCH/WRITE canary). Fix: prefetch depth lives in LDS (zero VGPR):
//   - V triple-buffer 3x16KB; tile kt+2 issued post-barrier(kt) into the
//     buffer freed by kt-1 (4 x global_load_lds of 1KB per wave).
//   - s_waitcnt vmcnt(6) lgkmcnt(0); s_barrier -- V(kt) landed, V(kt+1)'s 4
//     loads + K prefetch (2) STAY IN FLIGHT across the barrier (T3/T4).
//   - No key split: wave w owns channel tile ct=w for ALL 64 key tiles
//     (no combine epilogue). QK rotates: wave w produces q-subtile w&1 on
//     tiles of parity w>>1 (2 MFMA + 32 exp/turn, zero redundancy); P via
//     16KB double-buffered LDS.
//   Registers: of[2]=32acc + kf 8 + qf 4 + po 16 -> ~130 unified, no spill.
// LDS 64.5KB -> 2 blocks/CU (grid 512 = exact fill).
// ---------------------------------------------------------------------------
__global__ __launch_bounds__(256, 2)
void attn_kernel(const f16* __restrict__ Qt, const f16* __restrict__ Kt,
                 const f16* __restrict__ Vf, float* __restrict__ out)
{
    __shared__ __align__(16) unsigned char lds_raw[65536];
    // [0, 49152):     V tiles, 3 x 16384 B (tile kt in buf kt%3)
    // [49152, 65536): Pb f16 [2 buf][2 qs][4 kc][64 lane][8]
    // epilogue alias: Tb f32[128][68] at 0; ls_part f32[128] at 49152;
    //                 ls_inv f32[64] at 49664

    const int tid  = threadIdx.x;
    const int lane = tid & 63;
    const int w    = tid >> 6;         // channel tile ct = w
    const int qp   = w & 1;            // q-subtile this wave produces
    const int pw   = w >> 1;           // tile parity this wave produces
    const int b    = blockIdx.x & 7;
    const int qt   = blockIdx.x >> 3;  // 0..63
    const int q0   = qt*64;
    const int n32  = lane & 31;
    const int half = lane >> 5;

    const f16* vb = Vf + (size_t)b*64*16*512;    // tile stride 8192 f16 = 16384 B
    const f16* kb = Kt + (size_t)b*NN*16;
    const f16x8 qf = *(const f16x8*)&Qt[((size_t)b*NN + q0 + qp*32 + n32)*16 + half*8];

    f32x16 of0 = (f32x16)0.0f, of1 = (f32x16)0.0f;
    float ps[4] = {0.f, 0.f, 0.f, 0.f};

    f16* Pb = (f16*)(lds_raw + 49152);

    // each wave stages its quarter (4 KB) of a 16 KB tile: 4 x 1KB issues
#define STAGE(TILE, BUF)                                                              \
    {                                                                                 \
        const unsigned char* gsb = (const unsigned char*)vb + (size_t)(TILE)*16384    \
                                   + w*4096 + lane*16;                                \
        unsigned char* lsb = lds_raw + (BUF)*16384 + w*4096;                          \
        _Pragma("unroll")                                                             \
        for (int sp = 0; sp < 4; sp++) {                                              \
            __builtin_amdgcn_global_load_lds(                                         \
                (const __attribute__((address_space(1))) unsigned int*)(gsb + sp*1024), \
                (__attribute__((address_space(3))) unsigned int*)(lsb + sp*1024),     \
                16, 0, 0);                                                            \
        }                                                                             \
    }

    // prologue order matters for the vmcnt(6) algebra:
    // V(0) first, then K(first-producing-tile), then V(1).
    STAGE(0, 0)
    f16x8 kf0 = *(const f16x8*)&kb[((size_t)pw*64 + n32)*16 + half*8];
    f16x8 kf1 = *(const f16x8*)&kb[((size_t)pw*64 + 32 + n32)*16 + half*8];
    STAGE(1, 1)

    int vbuf = 0;                      // LDS buffer holding tile kt
    for (int kt = 0; kt < 64; ++kt) {
        const int cur = kt & 1;
        if (cur == pw) {               // producer for this tile's q-subtile qp
            f32x16 St0 = __builtin_amdgcn_mfma_f32_32x32x16_f16(kf0, qf, (f32x16)(-SHIFT), 0, 0, 0);
            f32x16 St1 = __builtin_amdgcn_mfma_f32_32x32x16_f16(kf1, qf, (f32x16)(-SHIFT), 0, 0, 0);
            int tl = kt + 2; if (tl > 63) tl = kt;
            kf0 = *(const f16x8*)&kb[((size_t)tl*64 + n32)*16 + half*8];
            kf1 = *(const f16x8*)&kb[((size_t)tl*64 + 32 + n32)*16 + half*8];
            f16x8 po[4];
            #pragma unroll
            for (int g = 0; g < 16; g++) {
                float e0 = EXP2(St0[g]); ps[g & 3] += e0; po[(g >> 3)][g & 7]     = (f16)e0;
                float e1 = EXP2(St1[g]); ps[g & 3] += e1; po[2 + (g >> 3)][g & 7] = (f16)e1;
            }
            f16* wr = Pb + ((size_t)(cur*2 + qp)*4*64 + lane)*8;
            #pragma unroll
            for (int kc = 0; kc < 4; kc++)
                *(f16x8*)&wr[kc*512] = po[kc];
        }
        // counted wait: V(kt) + P writes drained; V(kt+1) 4 loads + K 2 stay
        // in flight across the barrier.
        asm volatile("s_waitcnt vmcnt(6) lgkmcnt(0)\n\ts_barrier" ::: "memory");
        // stage tile kt+2 into the buffer freed by tile kt-1 (all waves past
        // PV(kt-1) after this barrier). Tail: re-stage 63 (dummy, never read)
        // to keep the vmcnt algebra uniform.
        {
            int tl = kt + 2; if (tl > 63) tl = 63;
            int sb = vbuf + 2; if (sb >= 3) sb -= 3;
            STAGE(tl, sb)
        }
        // PV: V fragments from LDS, P (both q-subtiles) from LDS
        {
            const f16* Vt = (const f16*)lds_raw + (size_t)vbuf*8192;
            const f16* Pc = Pb + (size_t)cur*4096;
            #pragma unroll
            for (int kc = 0; kc < 4; kc++) {
                f16x8 vc = *(const f16x8*)&Vt[((size_t)(kc*4 + w)*64 + lane)*8];
                f16x8 p0 = *(const f16x8*)&Pc[((size_t)kc*64 + lane)*8];
                f16x8 p1 = *(const f16x8*)&Pc[((size_t)(4 + kc)*64 + lane)*8];
                of0 = __builtin_amdgcn_mfma_f32_32x32x16_f16(p0, vc, of0, 0, 0, 0);
                of1 = __builtin_amdgcn_mfma_f32_32x32x16_f16(p1, vc, of1, 0, 0, 0);
            }
        }
        vbuf = (vbuf + 1 == 3) ? 0 : vbuf + 1;
    }
#undef STAGE

    // ---- epilogue: ls combine across parity pairs, normalize, transpose ----
    float ls = (ps[0] + ps[1]) + (ps[2] + ps[3]);
    ls += __shfl_xor(ls, 32);
    __syncthreads();                   // also drains dangling dummy stages
    float* ls_part = (float*)(lds_raw + 49152);
    float* ls_inv  = (float*)(lds_raw + 49664);
    if (lane < 32) ls_part[w*32 + n32] = ls;
    __syncthreads();
    if (w < 2 && lane < 32)
        ls_inv[w*32 + n32] = 1.0f / (ls_part[w*32 + n32] + ls_part[(w+2)*32 + n32]);
    __syncthreads();
    {
        float* Tb = (float*)lds_raw;   // [128 ch][68], aliases V buffers
        #pragma unroll
        for (int qs = 0; qs < 2; qs++) {
            #pragma unroll
            for (int j = 0; j < 4; j++) {
                f32x4v iv = *(const f32x4v*)&ls_inv[qs*32 + 8*j + 4*half];
                f32x4v o;
                #pragma unroll
                for (int e = 0; e < 4; e++)
                    o[e] = (qs ? of1 : of0)[4*j + e] * iv[e];
                *(f32x4v*)&Tb[(size_t)(w*32 + n32)*68 + qs*32 + 8*j + 4*half] = o;
            }
        }
    }
    __syncthreads();
    {
        const float* Tb = (const float*)lds_raw;
        #pragma unroll
        for (int it = 0; it < 8; it++) {
            int idx = it*256 + tid;
            int c = idx >> 4, qg = idx & 15;
            f32x4v v = *(const f32x4v*)&Tb[(size_t)c*68 + qg*4];
            // non-temporal: keep the 16 MB output stream out of L2
            __builtin_nontemporal_store(v,
                (f32x4v*)&out[((size_t)b*CC + c)*NN + q0 + qg*4]);
        }
    }
}

extern "C" void kernel_launch(void* const* d_in, const int* in_sizes, int n_in,
                              void* d_out, int out_size, void* d_ws, size_t ws_size,
                              hipStream_t stream) {
    const float* x  = (const float*)d_in[0];
    const float* Wq = (const float*)d_in[1];
    const float* bq = (const float*)d_in[2];
    const float* Wk = (const float*)d_in[3];
    const float* bk = (const float*)d_in[4];
    const float* Wv = (const float*)d_in[5];
    const float* bv = (const float*)d_in[6];
    float* out = (float*)d_out;

    // workspace: Qt,Kt f16 [B][N][16] (1MB each), Vf f16 sigma-fragments (8MB)
    f16* Qw = (f16*)d_ws;
    f16* Kw = Qw + (size_t)BB*NN*16;
    f16* Vw = Kw + (size_t)BB*NN*16;
    unsigned char* tail = (unsigned char*)d_out + (size_t)out_size*4 - WF_BYTES;
    f16*   Wf    = (f16*)tail;
    float* biasS = (float*)(tail + 49152);

    hipLaunchKernelGGL(prep_kernel, dim3(10), dim3(256), 0, stream,
                       Wq, bq, Wk, bk, Wv, bv, Wf, biasS);
    hipLaunchKernelGGL(proj_kernel, dim3(256), dim3(256), 0, stream,
                       x, Wf, biasS, Qw, Kw, Vw);
    hipLaunchKernelGGL(attn_kernel, dim3(512), dim3(256), 0, stream,
                       Qw, Kw, Vw, out);
}

// Round 9
// 136.547 us; speedup vs baseline: 1.5795x; 1.0894x over previous
//
#include <hip/hip_runtime.h>
#include <math.h>

#define BB 8
#define CC 128
#define NN 4096   // W*H

typedef _Float16 f16;
typedef _Float16 f16x4v __attribute__((ext_vector_type(4)));
typedef _Float16 f16x8 __attribute__((ext_vector_type(8)));
typedef float f32x4v __attribute__((ext_vector_type(4)));
typedef float f32x16 __attribute__((ext_vector_type(16)));

#if __has_builtin(__builtin_amdgcn_exp2f)
#define EXP2(x) __builtin_amdgcn_exp2f(x)
#else
#define EXP2(x) __expf((x)*0.69314718056f)
#endif

// Q rows pre-scaled by 0.25*log2(e): softmax exp is one native v_exp_f32;
// the -SHIFT bias rides in the MFMA C operand.
#define QSCALE 0.360673760222f   // 0.25 * log2(e)
#define SHIFT  5.770780163555f   // 4.0 * log2(e)

// Wf scratch lives in the tail of d_out (attn rewrites d_out afterwards).
#define WF_BYTES 65536

// ---------------------------------------------------------------------------
// prep: stack Wq*QSCALE (rows 0-15), Wk (16-31), Wv (32-159) as f16 in
// 32x32x16 A-fragment order. biasS f32[160] likewise stacked.
// ---------------------------------------------------------------------------
__global__ __launch_bounds__(256)
void prep_kernel(const float* __restrict__ Wq, const float* __restrict__ bq,
                 const float* __restrict__ Wk, const float* __restrict__ bk,
                 const float* __restrict__ Wv, const float* __restrict__ bv,
                 f16* __restrict__ Wf, float* __restrict__ biasS)
{
    const int tg = blockIdx.x*256 + threadIdx.x;   // 0..2559
    if (tg < 2560) {
        const int mt = tg >> 9, ks = (tg >> 6) & 7, l = tg & 63;
        const int n32 = l & 31, h = l >> 5;
        const int r = mt*32 + n32;
        f16x8 v8;
        #pragma unroll
        for (int i = 0; i < 8; i++) {
            int c = ks*16 + 8*h + i;
            float wv_;
            if (r < 16)      wv_ = QSCALE * Wq[r*CC + c];
            else if (r < 32) wv_ = Wk[(r-16)*CC + c];
            else             wv_ = Wv[(r-32)*CC + c];
            v8[i] = (f16)wv_;
        }
        *(f16x8*)&Wf[(size_t)tg*8] = v8;
    }
    if (blockIdx.x == 0 && threadIdx.x < 160) {
        int r = threadIdx.x;
        biasS[r] = r < 16 ? QSCALE*bq[r] : (r < 32 ? bk[r-16] : bv[r-32]);
    }
}

// ---------------------------------------------------------------------------
// proj r17: M-SPLIT for occupancy. Old proj ran grid 256 = 1 block/CU =
// 1 wave/SIMD -- zero wave-level latency hiding; every x HBM load, Wf L2
// load, and LDS transpose round-trip fully exposed (suspected source of the
// stable ~75us of non-attn time; roofline says ~6us).
// Now grid 512: bx = mh*256 + pt*8 + b; mh0 -> mt{0,1} (Q/K + V ch 0-31),
// mh1 -> mt{2,3,4} (V ch 32-127). Same total MFMA; x read twice (+2.7us
// HBM floor); 2 blocks/CU = 2 waves/SIMD + cross-block overlap; acc 80->48
// f32. Epilogue predicated by ct ownership (wave-uniform, no divergence).
// Vf layout unchanged:
//   Vf[b][kt64][frag=c16*4+ct][l][i] =
//     V[c=ct*32+(l&31)][key=kt64*64 + c16*16 + (i&3)+8*(i>>2)+4*(l>>5)]
// ---------------------------------------------------------------------------
__global__ __launch_bounds__(256)
void proj_kernel(const float* __restrict__ x, const f16* __restrict__ Wf,
                 const float* __restrict__ biasS,
                 f16* __restrict__ Qt, f16* __restrict__ Kt, f16* __restrict__ Vf)
{
    __shared__ __align__(16) f16 Vl[CC*140];   // 35 KB, stride 140 halfs

    const int tid  = threadIdx.x;
    const int lane = tid & 63;
    const int wv   = tid >> 6;
    const int bx   = blockIdx.x;
    const int b    = bx & 7;
    const int pt   = (bx >> 3) & 31;       // 0..31
    const int mh   = bx >> 8;              // 0: mt{0,1}, 1: mt{2,3,4}
    const int mt0  = mh ? 2 : 0;
    const int nmt  = mh ? 3 : 2;
    const int n32  = lane & 31;
    const int half = lane >> 5;
    const int p    = pt*128 + wv*32 + n32;

    const float* xp = x + (size_t)b*CC*NN + p;
    f16x8 xf[8];
    #pragma unroll
    for (int ks = 0; ks < 8; ks++) {
        float xv[8];
        #pragma unroll
        for (int i = 0; i < 8; i++)
            xv[i] = __builtin_nontemporal_load(&xp[(size_t)(ks*16 + 8*half + i)*NN]);
        #pragma unroll
        for (int i = 0; i < 8; i++) xf[ks][i] = (f16)xv[i];
    }

    f32x16 acc[3];
    #pragma unroll
    for (int m = 0; m < 3; m++) acc[m] = (f32x16)0.0f;
    #pragma unroll
    for (int ks = 0; ks < 8; ks++) {
        #pragma unroll
        for (int m = 0; m < 3; m++) {
            if (m < nmt) {
                f16x8 wfr = *(const f16x8*)&Wf[((size_t)((mt0 + m)*8 + ks)*64 + lane)*8];
                acc[m] = __builtin_amdgcn_mfma_f32_32x32x16_f16(wfr, xf[ks], acc[m], 0, 0, 0);
            }
        }
    }

    #pragma unroll
    for (int m = 0; m < 3; m++) {
        if (m < nmt) {
            #pragma unroll
            for (int q = 0; q < 4; q++) {
                float4 b4 = *(const float4*)&biasS[(mt0 + m)*32 + q*8 + 4*half];
                acc[m][q*4+0] += b4.x; acc[m][q*4+1] += b4.y;
                acc[m][q*4+2] += b4.z; acc[m][q*4+3] += b4.w;
            }
        }
    }

    if (mh == 0) {
        // acc[0] = mt0: rows 0-15 = Q, 16-31 = K
        size_t qkoff = ((size_t)b*NN + p)*16;
        f16x4v s0, s1, s2, s3;
        #pragma unroll
        for (int i = 0; i < 4; i++) {
            s0[i] = (f16)acc[0][i];    s1[i] = (f16)acc[0][4+i];
            s2[i] = (f16)acc[0][8+i];  s3[i] = (f16)acc[0][12+i];
        }
        *(f16x4v*)&Qt[qkoff + 4*half]     = s0;
        *(f16x4v*)&Qt[qkoff + 8 + 4*half] = s1;
        *(f16x4v*)&Kt[qkoff + 4*half]     = s2;
        *(f16x4v*)&Kt[qkoff + 8 + 4*half] = s3;
        // acc[1] = mt1: V channels 0-31 -> Vl rows 0-31
        #pragma unroll
        for (int g = 0; g < 16; g++) {
            int c = (g & 3) + 8*(g >> 2) + 4*half;
            Vl[c*140 + wv*32 + n32] = (f16)acc[1][g];
        }
    } else {
        // acc[0..2] = mt2..4: V channels 32-127 -> Vl rows 32-127
        #pragma unroll
        for (int m = 0; m < 3; m++) {
            #pragma unroll
            for (int g = 0; g < 16; g++) {
                int c = (m + 1)*32 + (g & 3) + 8*(g >> 2) + 4*half;
                Vl[c*140 + wv*32 + n32] = (f16)acc[m][g];
            }
        }
    }
    __syncthreads();

    // sigma-ordered Vf writeout; each mh writes only its own ct set.
    // item>>6 is wave-uniform -> the ownership predicate never diverges.
    #pragma unroll
    for (int pass = 0; pass < 8; pass++) {
        int item = pass*256 + tid;
        int l    = item & 63;
        int f    = (item >> 6) & 15;       // c16*4 + ct
        int ktl  = item >> 10;             // 0..1 (64-px tile within block)
        int c16  = f >> 2, ct = f & 3;
        bool mine = mh ? (ct != 0) : (ct == 0);
        if (mine) {
            int li = l & 31, h2 = l >> 5;
            const f16* src = &Vl[(ct*32 + li)*140 + ktl*64 + c16*16 + 4*h2];
            f16x4v lo = *(const f16x4v*)&src[0];
            f16x4v hi = *(const f16x4v*)&src[8];
            f16x8 v8;
            #pragma unroll
            for (int i = 0; i < 4; i++) { v8[i] = lo[i]; v8[4+i] = hi[i]; }
            int ktg = pt*2 + ktl;          // 64-key tile index
            *(f16x8*)&Vf[((((size_t)b*64 + ktg)*16 + c16*4 + ct)*64 + l)*8] = v8;
        }
    }
}

// ---------------------------------------------------------------------------
// Attention r10 (champion, 54.0us) -- reverted byte-exact. Kill the QK/exp
// redundancy via LDS P-exchange. Grid 512 (b = bx&7, qt = bx>>3 -> 64
// queries), block 256 = 4 waves: wave w: cp = w&1 (channel pair + q-tile
// owner), kh = w>>1 (key half). Per iter each wave computes QK^T+exp for ITS
// q-tile only, exchanges P through double-buffered LDS, then PV for both
// q-tiles (V fragments read once, feed 2 MFMAs).
// ---------------------------------------------------------------------------
__global__ __launch_bounds__(256, 2)
void attn_kernel(const f16* __restrict__ Qt, const f16* __restrict__ Kt,
                 const f16* __restrict__ Vf, float* __restrict__ out)
{
    __shared__ __align__(16) unsigned char lds_raw[53504];
    // main loop:  Pex [4 waves][2 buf][4 kc][64 lanes][16B] = 32 KB at 0
    // epilogue:   combine regions 2 x 9216 at 0; ls_inv f32[64] at 18432;
    //             Tb f32[128][68] at 18688 (all alias Pex; phases barriered)

    const int tid  = threadIdx.x;
    const int lane = tid & 63;
    const int w    = tid >> 6;
    const int cp   = w & 1;            // channel pair + q-tile ownership
    const int kh   = w >> 1;           // key half: kt = kh (mod 2)
    const int b    = blockIdx.x & 7;
    const int qt   = blockIdx.x >> 3;  // 0..63
    const int q0   = qt*64;
    const int n32  = lane & 31;
    const int half = lane >> 5;

    const f16* vb = Vf + (size_t)b*64*16*512;
    const f16* kb = Kt + (size_t)b*NN*16;
    // own q-tile only: A (q0..q0+31) if cp==0, B (q0+32..) if cp==1
    const f16x8 qf = *(const f16x8*)&Qt[((size_t)b*NN + q0 + cp*32 + n32)*16 + half*8];

    f32x16 ofA[2], ofB[2];
    #pragma unroll
    for (int c = 0; c < 2; c++) { ofA[c] = (f32x16)0.0f; ofB[c] = (f32x16)0.0f; }
    float ps[4] = {0.f, 0.f, 0.f, 0.f};

    // prime the pipeline: K + this wave's 8 V fragments for kt = kh
    f16x8 kf0 = *(const f16x8*)&kb[((size_t)kh*64 + n32)*16 + half*8];
    f16x8 kf1 = *(const f16x8*)&kb[((size_t)kh*64 + 32 + n32)*16 + half*8];
    f16x8 vpf[8];
    {
        const f16* vt = vb + (size_t)kh*8192;
        #pragma unroll
        for (int kc = 0; kc < 4; kc++)
            #pragma unroll
            for (int j = 0; j < 2; j++)
                vpf[kc*2+j] = *(const f16x8*)&vt[((size_t)(kc*4 + 2*cp + j)*64 + lane)*8];
    }

    f16* Pex = (f16*)lds_raw;
    int pb = 0;

    for (int kt = kh; kt < NN/64; kt += 2) {
        const int ktn = (kt + 2 < NN/64) ? kt + 2 : kt;
        f16x8 kf0n = *(const f16x8*)&kb[((size_t)ktn*64 + n32)*16 + half*8];
        f16x8 kf1n = *(const f16x8*)&kb[((size_t)ktn*64 + 32 + n32)*16 + half*8];

        // own q-tile: S^T = K * qf, P = 2^(S - SHIFT)
        f16x8 po[4];
        {
            f32x16 St0 = __builtin_amdgcn_mfma_f32_32x32x16_f16(kf0, qf, (f32x16)(-SHIFT), 0, 0, 0);
            f32x16 St1 = __builtin_amdgcn_mfma_f32_32x32x16_f16(kf1, qf, (f32x16)(-SHIFT), 0, 0, 0);
            #pragma unroll
            for (int g = 0; g < 16; g++) {
                float e0 = EXP2(St0[g]); ps[g & 3] += e0; po[(g >> 3)][g & 7]     = (f16)e0;
                float e1 = EXP2(St1[g]); ps[g & 3] += e1; po[2 + (g >> 3)][g & 7] = (f16)e1;
            }
        }

        // ---- P exchange with partner wave (w^1): same kh, other q-tile ----
        {
            f16* wr = &Pex[((size_t)(w*2 + pb)*4*64 + lane)*8];
            #pragma unroll
            for (int kc = 0; kc < 4; kc++)
                *(f16x8*)&wr[kc*512] = po[kc];
        }
        __syncthreads();
        f16x8 pq[4];
        {
            const f16* rd = &Pex[((size_t)((w^1)*2 + pb)*4*64 + lane)*8];
            #pragma unroll
            for (int kc = 0; kc < 4; kc++)
                pq[kc] = *(const f16x8*)&rd[kc*512];
        }

        const f16* vtn = vb + (size_t)ktn*8192;
#define PV_BLOCK(PA, PB)                                                              \
        _Pragma("unroll")                                                             \
        for (int kc = 0; kc < 4; kc++) {                                              \
            _Pragma("unroll")                                                         \
            for (int j = 0; j < 2; j++) {                                             \
                const int ii = kc*2 + j;                                              \
                f16x8 vc = vpf[ii];                                                   \
                vpf[ii] = *(const f16x8*)&vtn[((size_t)(kc*4 + 2*cp + j)*64 + lane)*8]; \
                ofA[j] = __builtin_amdgcn_mfma_f32_32x32x16_f16(PA[kc], vc, ofA[j], 0, 0, 0); \
                ofB[j] = __builtin_amdgcn_mfma_f32_32x32x16_f16(PB[kc], vc, ofB[j], 0, 0, 0); \
            }                                                                         \
        }
        if (cp == 0) { PV_BLOCK(po, pq) }
        else         { PV_BLOCK(pq, po) }
#undef PV_BLOCK

        kf0 = kf0n; kf1 = kf1n; pb ^= 1;
    }

    // per-lane softmax denominator for own q-tile (this wave's key half)
    float ls = (ps[0] + ps[1]) + (ps[2] + ps[3]);
    ls += __shfl_xor(ls, 32);

    // ---- combine the 2-way key split (wave pairs (0,2) and (1,3)) ----
    __syncthreads();
    if (w >= 2) {
        unsigned char* base = lds_raw + (size_t)cp*9216 + (size_t)lane*144;
        #pragma unroll
        for (int a = 0; a < 4; a++) {        // a = qtsel*2 + ctl
            #pragma unroll
            for (int h = 0; h < 2; h++) {
                f16x8 t;
                #pragma unroll
                for (int jj = 0; jj < 8; jj++)
                    t[jj] = (f16)((a < 2 ? ofA[a & 1] : ofB[a & 1])[h*8 + jj]);
                *(f16x8*)(base + a*32 + h*16) = t;
            }
        }
        *(float*)(base + 128) = ls;          // own q-tile's denominator partial
    }
    __syncthreads();
    if (w < 2) {
        unsigned char* base = lds_raw + (size_t)cp*9216 + (size_t)lane*144;
        #pragma unroll
        for (int a = 0; a < 4; a++) {
            #pragma unroll
            for (int h = 0; h < 2; h++) {
                f16x8 t = *(const f16x8*)(base + a*32 + h*16);
                #pragma unroll
                for (int jj = 0; jj < 8; jj++) {
                    float v = (float)t[jj];
                    if (a < 2) ofA[a & 1][h*8 + jj] += v;
                    else       ofB[a & 1][h*8 + jj] += v;
                }
            }
        }
        ls += *(const float*)(base + 128);
        // lead wave (0,cp) now has the full denominator for q-tile cp
        float* ls_inv = (float*)(lds_raw + 18432);
        if (lane < 32) ls_inv[cp*32 + n32] = 1.f / ls;
    }
    __syncthreads();

    // normalize + transpose into Tb[c][q] (waves 0,1 own 64 channels each)
    if (w < 2) {
        const float* ls_inv = (const float*)(lds_raw + 18432);
        float* Tb = (float*)(lds_raw + 18688);
        #pragma unroll
        for (int qts = 0; qts < 2; qts++) {
            #pragma unroll
            for (int j = 0; j < 4; j++) {
                f32x4v iv = *(const f32x4v*)&ls_inv[qts*32 + 8*j + 4*half];
                #pragma unroll
                for (int ctl = 0; ctl < 2; ctl++) {
                    const int c = (2*cp + ctl)*32 + n32;
                    f32x4v o;
                    #pragma unroll
                    for (int e = 0; e < 4; e++)
                        o[e] = (qts ? ofB[ctl] : ofA[ctl])[4*j + e] * iv[e];
                    *(f32x4v*)&Tb[(size_t)c*68 + qts*32 + 8*j + 4*half] = o;
                }
            }
        }
    }
    __syncthreads();
    {
        const float* Tb = (const float*)(lds_raw + 18688);
        #pragma unroll
        for (int it = 0; it < 8; it++) {
            int idx = it*256 + tid;
            int c = idx >> 4, qg = idx & 15;
            f32x4v v = *(const f32x4v*)&Tb[(size_t)c*68 + qg*4];
            // non-temporal: keep the 16 MB output stream out of L2
            __builtin_nontemporal_store(v,
                (f32x4v*)&out[((size_t)b*CC + c)*NN + q0 + qg*4]);
        }
    }
}

extern "C" void kernel_launch(void* const* d_in, const int* in_sizes, int n_in,
                              void* d_out, int out_size, void* d_ws, size_t ws_size,
                              hipStream_t stream) {
    const float* x  = (const float*)d_in[0];
    const float* Wq = (const float*)d_in[1];
    const float* bq = (const float*)d_in[2];
    const float* Wk = (const float*)d_in[3];
    const float* bk = (const float*)d_in[4];
    const float* Wv = (const float*)d_in[5];
    const float* bv = (const float*)d_in[6];
    float* out = (float*)d_out;

    // workspace: Qt,Kt f16 [B][N][16] (1MB each), Vf f16 sigma-fragments (8MB)
    f16* Qw = (f16*)d_ws;
    f16* Kw = Qw + (size_t)BB*NN*16;
    f16* Vw = Kw + (size_t)BB*NN*16;
    unsigned char* tail = (unsigned char*)d_out + (size_t)out_size*4 - WF_BYTES;
    f16*   Wf    = (f16*)tail;
    float* biasS = (float*)(tail + 49152);

    hipLaunchKernelGGL(prep_kernel, dim3(10), dim3(256), 0, stream,
                       Wq, bq, Wk, bk, Wv, bv, Wf, biasS);
    hipLaunchKernelGGL(proj_kernel, dim3(512), dim3(256), 0, stream,
                       x, Wf, biasS, Qw, Kw, Vw);
    hipLaunchKernelGGL(attn_kernel, dim3(512), dim3(256), 0, stream,
                       Qw, Kw, Vw, out);
}

// Round 10
// 133.842 us; speedup vs baseline: 1.6114x; 1.0202x over previous
//
#include <hip/hip_runtime.h>
#include <math.h>

#define BB 8
#define CC 128
#define NN 4096   // W*H

typedef _Float16 f16;
typedef _Float16 f16x4v __attribute__((ext_vector_type(4)));
typedef _Float16 f16x8 __attribute__((ext_vector_type(8)));
typedef float f32x4v __attribute__((ext_vector_type(4)));
typedef float f32x16 __attribute__((ext_vector_type(16)));

#if __has_builtin(__builtin_amdgcn_exp2f)
#define EXP2(x) __builtin_amdgcn_exp2f(x)
#else
#define EXP2(x) __expf((x)*0.69314718056f)
#endif

// Q rows pre-scaled by 0.25*log2(e): softmax exp is one native v_exp_f32;
// the -SHIFT bias rides in the MFMA C operand.
#define QSCALE 0.360673760222f   // 0.25 * log2(e)
#define SHIFT  5.770780163555f   // 4.0 * log2(e)

// Wf scratch lives in the tail of d_out (attn rewrites d_out afterwards).
#define WF_BYTES 65536

// ---------------------------------------------------------------------------
// prep: stack Wq*QSCALE (rows 0-15), Wk (16-31), Wv (32-159) as f16 in
// 32x32x16 A-fragment order. biasS f32[160] likewise stacked.
// ---------------------------------------------------------------------------
__global__ __launch_bounds__(256)
void prep_kernel(const float* __restrict__ Wq, const float* __restrict__ bq,
                 const float* __restrict__ Wk, const float* __restrict__ bk,
                 const float* __restrict__ Wv, const float* __restrict__ bv,
                 f16* __restrict__ Wf, float* __restrict__ biasS)
{
    const int tg = blockIdx.x*256 + threadIdx.x;   // 0..2559
    if (tg < 2560) {
        const int mt = tg >> 9, ks = (tg >> 6) & 7, l = tg & 63;
        const int n32 = l & 31, h = l >> 5;
        const int r = mt*32 + n32;
        f16x8 v8;
        #pragma unroll
        for (int i = 0; i < 8; i++) {
            int c = ks*16 + 8*h + i;
            float wv_;
            if (r < 16)      wv_ = QSCALE * Wq[r*CC + c];
            else if (r < 32) wv_ = Wk[(r-16)*CC + c];
            else             wv_ = Wv[(r-32)*CC + c];
            v8[i] = (f16)wv_;
        }
        *(f16x8*)&Wf[(size_t)tg*8] = v8;
    }
    if (blockIdx.x == 0 && threadIdx.x < 160) {
        int r = threadIdx.x;
        biasS[r] = r < 16 ? QSCALE*bq[r] : (r < 32 ? bk[r-16] : bv[r-32]);
    }
}

// ---------------------------------------------------------------------------
// Projection (reverted to the r2/r10-era version -- the r17 M-split was a
// null result, e2e 136.5 vs 133.9): grid 256 (b = bx&7, pt = bx>>3), block
// 256 = 4 waves, wave = 32-pixel n-tile, K=128 (8 ksteps), 40 MFMAs/wave.
// Epilogue: Qt/Kt pixel-major; V via LDS -> sigma-ordered Vf:
//   Vf[b][kt64][frag=kc*4+ct][l][i] =
//     V[c=ct*32+(l&31)][key=kt64*64 + kc*16 + (i&3)+8*(i>>2)+4*(l>>5)]
// ---------------------------------------------------------------------------
__global__ __launch_bounds__(256)
void proj_kernel(const float* __restrict__ x, const f16* __restrict__ Wf,
                 const float* __restrict__ biasS,
                 f16* __restrict__ Qt, f16* __restrict__ Kt, f16* __restrict__ Vf)
{
    __shared__ __align__(16) f16 Vl[CC*140];   // 35 KB, stride 140 halfs

    const int tid  = threadIdx.x;
    const int lane = tid & 63;
    const int wv   = tid >> 6;
    const int b    = blockIdx.x & 7;
    const int pt   = blockIdx.x >> 3;      // 0..31
    const int n32  = lane & 31;
    const int half = lane >> 5;
    const int p    = pt*128 + wv*32 + n32;

    const float* xp = x + (size_t)b*CC*NN + p;
    f16x8 xf[8];
    #pragma unroll
    for (int ks = 0; ks < 8; ks++) {
        float xv[8];
        #pragma unroll
        for (int i = 0; i < 8; i++)
            xv[i] = __builtin_nontemporal_load(&xp[(size_t)(ks*16 + 8*half + i)*NN]);
        #pragma unroll
        for (int i = 0; i < 8; i++) xf[ks][i] = (f16)xv[i];
    }

    f32x16 acc[5];
    #pragma unroll
    for (int mt = 0; mt < 5; mt++) acc[mt] = (f32x16)0.0f;
    #pragma unroll
    for (int ks = 0; ks < 8; ks++) {
        #pragma unroll
        for (int mt = 0; mt < 5; mt++) {
            f16x8 wfr = *(const f16x8*)&Wf[((size_t)(mt*8 + ks)*64 + lane)*8];
            acc[mt] = __builtin_amdgcn_mfma_f32_32x32x16_f16(wfr, xf[ks], acc[mt], 0, 0, 0);
        }
    }

    #pragma unroll
    for (int mt = 0; mt < 5; mt++) {
        #pragma unroll
        for (int q = 0; q < 4; q++) {
            float4 b4 = *(const float4*)&biasS[mt*32 + q*8 + 4*half];
            acc[mt][q*4+0] += b4.x; acc[mt][q*4+1] += b4.y;
            acc[mt][q*4+2] += b4.z; acc[mt][q*4+3] += b4.w;
        }
    }

    // mt0: rows 0-15 = Q, 16-31 = K
    {
        size_t qkoff = ((size_t)b*NN + p)*16;
        f16x4v s0, s1, s2, s3;
        #pragma unroll
        for (int i = 0; i < 4; i++) {
            s0[i] = (f16)acc[0][i];    s1[i] = (f16)acc[0][4+i];
            s2[i] = (f16)acc[0][8+i];  s3[i] = (f16)acc[0][12+i];
        }
        *(f16x4v*)&Qt[qkoff + 4*half]     = s0;
        *(f16x4v*)&Qt[qkoff + 8 + 4*half] = s1;
        *(f16x4v*)&Kt[qkoff + 4*half]     = s2;
        *(f16x4v*)&Kt[qkoff + 8 + 4*half] = s3;
    }

    // mt1-4: V channels -> LDS [c][local pixel]
    #pragma unroll
    for (int mt = 1; mt < 5; mt++) {
        #pragma unroll
        for (int g = 0; g < 16; g++) {
            int c = (mt-1)*32 + (g & 3) + 8*(g >> 2) + 4*half;
            Vl[c*140 + wv*32 + n32] = (f16)acc[mt][g];
        }
    }
    __syncthreads();

    // sigma-ordered Vf writeout
    #pragma unroll
    for (int pass = 0; pass < 8; pass++) {
        int item = pass*256 + tid;
        int l    = item & 63;
        int f    = (item >> 6) & 15;       // kc*4 + ct
        int ktl  = item >> 10;             // 0..1 (64-px tile within block)
        int c16  = f >> 2, ct = f & 3;
        int li   = l & 31, h2 = l >> 5;
        const f16* src = &Vl[(ct*32 + li)*140 + ktl*64 + c16*16 + 4*h2];
        f16x4v lo = *(const f16x4v*)&src[0];
        f16x4v hi = *(const f16x4v*)&src[8];
        f16x8 v8;
        #pragma unroll
        for (int i = 0; i < 4; i++) { v8[i] = lo[i]; v8[4+i] = hi[i]; }
        int ktg = pt*2 + ktl;              // 64-key tile index
        *(f16x8*)&Vf[((((size_t)b*64 + ktg)*16 + c16*4 + ct)*64 + l)*8] = v8;
    }
}

// ---------------------------------------------------------------------------
// Attention r18: 128 queries/block to HALVE the read traffic (the measured
// binding constraint: r10 = 666 MB at its achieved 12.3 TB/s = the 54us).
// Grid 256 (b = bx&7 -> per-XCD batch L2 locality, qt = bx>>3 -> 128q),
// block 512 = 8 waves: wave w = (ct = w&3 channel tile, kh = w>>2 key
// parity). Per round (1 key tile of parity kh): EVERY wave symmetrically:
//   produce P for its own q-subtile ct (2 QK MFMA + 32 exp, no redundancy)
//   -> write 4 frags to double-buffered Pex -> lgkm-only barrier (V loads
//   stay in flight) -> read all 4 qsubs' P (16 ds_read_b128) -> PV: 4 V
//   frags feed 16 MFMAs (V read once per block for all 128 queries).
// Total per-wave work identical to r10 (576 MFMA, 1024 exp); read traffic
// 288 MB vs 666. V prefetch depth 2 tiles costs only vpf[8]=32 VGPR here
// (half of r15's spilling shape). ~190 unified regs, launch_bounds(512,1).
// Epilogue: kh-pair of-combine (f16, 144B stride) + ls merge + 2-pass Tb.
// ---------------------------------------------------------------------------
__global__ __launch_bounds__(512, 1)
void attn_kernel(const f16* __restrict__ Qt, const f16* __restrict__ Kt,
                 const f16* __restrict__ Vf, float* __restrict__ out)
{
    __shared__ __align__(16) unsigned char lds_raw[65536];
    // main loop: Pex f16 [2 pb][2 kh][4 s][4 kc][64 lane][16B] = 64 KB
    // epilogue (aliased, barrier-separated):
    //   comb [4 ct] x (64 lanes x 144B) = 36864 at 0 (waves kh=1 dump of)
    //   lsb f32[8][32] at 36864; ls_inv f32[128] at 37888
    //   Tb f32[128][68] = 34816 at 0 (over comb; comb consumed first)

    const int tid  = threadIdx.x;
    const int lane = tid & 63;
    const int w    = tid >> 6;         // 0..7
    const int ct   = w & 3;            // channel tile + own q-subtile
    const int kh   = w >> 2;           // key parity
    const int b    = blockIdx.x & 7;
    const int qt   = blockIdx.x >> 3;  // 0..31
    const int q0   = qt*128;
    const int n32  = lane & 31;
    const int half = lane >> 5;

    const f16* vb = Vf + (size_t)b*64*16*512;    // tile stride 8192 f16
    const f16* kb = Kt + (size_t)b*NN*16;
    // own q-subtile: queries q0 + ct*32 .. +31
    const f16x8 qf = *(const f16x8*)&Qt[((size_t)b*NN + q0 + ct*32 + n32)*16 + half*8];

    f32x16 of0 = (f32x16)0.0f, of1 = (f32x16)0.0f;
    f32x16 of2 = (f32x16)0.0f, of3 = (f32x16)0.0f;
    float ps[4] = {0.f, 0.f, 0.f, 0.f};

    f16* Pex = (f16*)lds_raw;

    // ---- depth-2 prologue: tiles t0 = kh*? -> this wave's tiles are
    // t(r) = 2r + kh, r = 0..31. Slot A holds t(2i), slot B t(2i+1).
    f16x8 kfA0 = *(const f16x8*)&kb[((size_t)(kh)*64 + n32)*16 + half*8];
    f16x8 kfA1 = *(const f16x8*)&kb[((size_t)(kh)*64 + 32 + n32)*16 + half*8];
    f16x8 kfB0 = *(const f16x8*)&kb[((size_t)(kh+2)*64 + n32)*16 + half*8];
    f16x8 kfB1 = *(const f16x8*)&kb[((size_t)(kh+2)*64 + 32 + n32)*16 + half*8];
    f16x8 vpfA[4], vpfB[4];
    {
        const f16* vtA = vb + (size_t)(kh)*8192;
        const f16* vtB = vb + (size_t)(kh+2)*8192;
        #pragma unroll
        for (int kc = 0; kc < 4; kc++) {
            vpfA[kc] = *(const f16x8*)&vtA[((size_t)(kc*4 + ct)*64 + lane)*8];
            vpfB[kc] = *(const f16x8*)&vtB[((size_t)(kc*4 + ct)*64 + lane)*8];
        }
    }

    // STEP: process key tile T (K in KF*, V in VPF), P round-buffer PB;
    // prefetch tile T+4 into the same registers (clamped dummy at tail).
#define STEP(T, KF0, KF1, VPF, PB)                                                    \
    {                                                                                 \
        f32x16 St0 = __builtin_amdgcn_mfma_f32_32x32x16_f16(KF0, qf, (f32x16)(-SHIFT), 0, 0, 0); \
        f32x16 St1 = __builtin_amdgcn_mfma_f32_32x32x16_f16(KF1, qf, (f32x16)(-SHIFT), 0, 0, 0); \
        int tl = (T) + 4; if (tl > 63) tl = (T);                                      \
        KF0 = *(const f16x8*)&kb[((size_t)tl*64 + n32)*16 + half*8];                  \
        KF1 = *(const f16x8*)&kb[((size_t)tl*64 + 32 + n32)*16 + half*8];             \
        f16x8 po[4];                                                                  \
        _Pragma("unroll")                                                             \
        for (int g = 0; g < 16; g++) {                                                \
            float e0 = EXP2(St0[g]); ps[g & 3] += e0; po[(g >> 3)][g & 7]     = (f16)e0; \
            float e1 = EXP2(St1[g]); ps[g & 3] += e1; po[2 + (g >> 3)][g & 7] = (f16)e1; \
        }                                                                             \
        {                                                                             \
            f16* wr = &Pex[(((size_t)((PB)*2 + kh)*16 + ct*4)*64 + lane)*8];          \
            _Pragma("unroll")                                                         \
            for (int kc = 0; kc < 4; kc++) *(f16x8*)&wr[kc*512] = po[kc];             \
        }                                                                             \
        asm volatile("s_waitcnt lgkmcnt(0)\n\ts_barrier" ::: "memory");               \
        const f16* vtn = vb + (size_t)tl*8192;                                        \
        _Pragma("unroll")                                                             \
        for (int kc = 0; kc < 4; kc++) {                                              \
            f16x8 vc = VPF[kc];                                                       \
            VPF[kc] = *(const f16x8*)&vtn[((size_t)(kc*4 + ct)*64 + lane)*8];         \
            const f16* rdb = &Pex[(((size_t)((PB)*2 + kh)*16 + kc)*64 + lane)*8];     \
            f16x8 p0 = *(const f16x8*)&rdb[0*4*512];                                  \
            f16x8 p1 = *(const f16x8*)&rdb[1*4*512];                                  \
            f16x8 p2 = *(const f16x8*)&rdb[2*4*512];                                  \
            f16x8 p3 = *(const f16x8*)&rdb[3*4*512];                                  \
            of0 = __builtin_amdgcn_mfma_f32_32x32x16_f16(p0, vc, of0, 0, 0, 0);       \
            of1 = __builtin_amdgcn_mfma_f32_32x32x16_f16(p1, vc, of1, 0, 0, 0);       \
            of2 = __builtin_amdgcn_mfma_f32_32x32x16_f16(p2, vc, of2, 0, 0, 0);       \
            of3 = __builtin_amdgcn_mfma_f32_32x32x16_f16(p3, vc, of3, 0, 0, 0);       \
        }                                                                             \
    }

    for (int i = 0; i < 16; ++i) {
        const int t = 4*i + kh;
        STEP(t,     kfA0, kfA1, vpfA, 0)
        STEP(t + 2, kfB0, kfB1, vpfB, 1)
    }
#undef STEP

    // per-lane denominator partial for own q-subtile (this wave's parity)
    float ls = (ps[0] + ps[1]) + (ps[2] + ps[3]);
    ls += __shfl_xor(ls, 32);

    // ---- combine kh pairs: waves (ct,1) dump of+ls; waves (ct,0) add ----
    __syncthreads();
    float* lsb = (float*)(lds_raw + 36864);      // [8][32]
    if (lane < 32) lsb[w*32 + n32] = ls;
    if (kh == 1) {
        unsigned char* base = lds_raw + (size_t)ct*9216 + (size_t)lane*144;
        #pragma unroll
        for (int s = 0; s < 4; s++) {
            const f32x16& o = s == 0 ? of0 : (s == 1 ? of1 : (s == 2 ? of2 : of3));
            #pragma unroll
            for (int h = 0; h < 2; h++) {
                f16x8 tv;
                #pragma unroll
                for (int jj = 0; jj < 8; jj++) tv[jj] = (f16)o[h*8 + jj];
                *(f16x8*)(base + s*32 + h*16) = tv;
            }
        }
    }
    __syncthreads();
    float* ls_inv = (float*)(lds_raw + 37888);   // [128]
    if (kh == 0) {
        unsigned char* base = lds_raw + (size_t)ct*9216 + (size_t)lane*144;
        #pragma unroll
        for (int s = 0; s < 4; s++) {
            f32x16& o = s == 0 ? of0 : (s == 1 ? of1 : (s == 2 ? of2 : of3));
            #pragma unroll
            for (int h = 0; h < 2; h++) {
                f16x8 tv = *(const f16x8*)(base + s*32 + h*16);
                #pragma unroll
                for (int jj = 0; jj < 8; jj++) o[h*8 + jj] += (float)tv[jj];
            }
        }
        if (lane < 32)
            ls_inv[ct*32 + n32] = 1.f / (lsb[w*32 + n32] + lsb[(w+4)*32 + n32]);
    }
    __syncthreads();

    // ---- normalize + transpose + store, two 64-query passes ----
    float* Tb = (float*)lds_raw;                 // [128][68], over comb region
    #pragma unroll
    for (int pass = 0; pass < 2; pass++) {
        if (kh == 0) {
            #pragma unroll
            for (int sl = 0; sl < 2; sl++) {
                const int s = pass*2 + sl;
                const f32x16& o = s == 0 ? of0 : (s == 1 ? of1 : (s == 2 ? of2 : of3));
                #pragma unroll
                for (int j = 0; j < 4; j++) {
                    f32x4v iv = *(const f32x4v*)&ls_inv[s*32 + 8*j + 4*half];
                    f32x4v ov;
                    #pragma unroll
                    for (int e = 0; e < 4; e++) ov[e] = o[4*j + e] * iv[e];
                    *(f32x4v*)&Tb[(size_t)(ct*32 + n32)*68 + sl*32 + 8*j + 4*half] = ov;
                }
            }
        }
        __syncthreads();
        #pragma unroll
        for (int it = 0; it < 4; it++) {
            int idx = it*512 + tid;              // 0..2047
            int c = idx >> 4, qg = idx & 15;
            f32x4v v = *(const f32x4v*)&Tb[(size_t)c*68 + qg*4];
            // non-temporal: keep the 16 MB output stream out of L2
            __builtin_nontemporal_store(v,
                (f32x4v*)&out[((size_t)b*CC + c)*NN + q0 + pass*64 + qg*4]);
        }
        if (pass == 0) __syncthreads();
    }
}

extern "C" void kernel_launch(void* const* d_in, const int* in_sizes, int n_in,
                              void* d_out, int out_size, void* d_ws, size_t ws_size,
                              hipStream_t stream) {
    const float* x  = (const float*)d_in[0];
    const float* Wq = (const float*)d_in[1];
    const float* bq = (const float*)d_in[2];
    const float* Wk = (const float*)d_in[3];
    const float* bk = (const float*)d_in[4];
    const float* Wv = (const float*)d_in[5];
    const float* bv = (const float*)d_in[6];
    float* out = (float*)d_out;

    // workspace: Qt,Kt f16 [B][N][16] (1MB each), Vf f16 sigma-fragments (8MB)
    f16* Qw = (f16*)d_ws;
    f16* Kw = Qw + (size_t)BB*NN*16;
    f16* Vw = Kw + (size_t)BB*NN*16;
    unsigned char* tail = (unsigned char*)d_out + (size_t)out_size*4 - WF_BYTES;
    f16*   Wf    = (f16*)tail;
    float* biasS = (float*)(tail + 49152);

    hipLaunchKernelGGL(prep_kernel, dim3(10), dim3(256), 0, stream,
                       Wq, bq, Wk, bk, Wv, bv, Wf, biasS);
    hipLaunchKernelGGL(proj_kernel, dim3(256), dim3(256), 0, stream,
                       x, Wf, biasS, Qw, Kw, Vw);
    hipLaunchKernelGGL(attn_kernel, dim3(256), dim3(512), 0, stream,
                       Qw, Kw, Vw, out);
}